// Round 6
// baseline (105.146 us; speedup 1.0000x reference)
//
#include <hip/hip_runtime.h>
#include <math.h>

// Problem sizes
constexpr int NB = 2048;  // batch
constexpr int ND = 32;    // data dim (x has ND+1 cols; col ND is replaced by t)
constexpr int NH = 512;   // hidden
constexpr int NKI = NH / 32;  // K-iterations of 32 per MFMA chain = 16

typedef __bf16 bf16x8 __attribute__((ext_vector_type(8)));
typedef __bf16 bf16x4 __attribute__((ext_vector_type(4)));
typedef float floatx4 __attribute__((ext_vector_type(4)));

__device__ inline float fast_tanh(float x) {
  float e = __expf(2.f * x);
  return 1.f - 2.f / (e + 1.f);
}

// Fragment pack index: elem = ((tile*nki + ki)*64 + lane)*8 + j
// A-frag (16x16x32): row m = tile*16 + (lane&15), k = ki*32 + (lane>>4)*8 + j
// B-frag:            col n = tile*16 + (lane&15), k = ki*32 + (lane>>4)*8 + j
// C/D frag:          col = lane&15, row = (lane>>4)*4 + reg   [m89-verified]

// ---------------------------------------------------------------------------
// Kernel 0: weight prep, load-balanced: every thread packs a 4-elem chunk of
// BOTH W2p and Mp (M[j,n] = W2[j,n]*G[n,j], G[n,j]=sum_i W3[n,i]*W1[i,j]).
// Also W3T (32x512 transpose), W1p (B-frag, K padded to 64), zero d_out.
// ---------------------------------------------------------------------------
__global__ __launch_bounds__(256) void k_pre(
    const float* __restrict__ W1, const float* __restrict__ W2,
    const float* __restrict__ W3, __bf16* __restrict__ W2p,
    __bf16* __restrict__ Mp, float* __restrict__ W3T,
    __bf16* __restrict__ W1p, float* __restrict__ out) {
  int g = blockIdx.x * 256 + threadIdx.x;  // 0..65535
  for (int idx = g; idx < NB * (ND + 1); idx += 65536) out[idx] = 0.f;
  if (g < ND * NH)  // W3T[i][k] = W3[k][i]
    W3T[g] = W3[(g & (NH - 1)) * ND + (g >> 9)];
  if (g < 4096) {   // W1p: ct(32) x ki(2) x lane(64), 8 bf16 each
    int lane1 = g & 63;
    int ki1 = (g >> 6) & 1;
    int ct1 = g >> 7;
    int n1 = ct1 * 16 + (lane1 & 15);
    int k0 = ki1 * 32 + (lane1 >> 4) * 8;
    __bf16 v[8];
#pragma unroll
    for (int j = 0; j < 8; ++j) {
      int k = k0 + j;
      v[j] = (k <= ND) ? (__bf16)W1[k * NH + n1] : (__bf16)0.f;
    }
    *(bf16x8*)(W1p + (long)g * 8) = *(bf16x8*)v;
  }

  // 4-element chunk coords within the B-frag pack
  int e = g * 4;                        // 0..262143, multiple of 4
  int lane = (e >> 3) & 63;
  int ki = (e >> 9) & (NKI - 1);
  int ct = e >> 13;                     // 0..31
  int n = ct * 16 + (lane & 15);        // output column (hidden-2 index)
  int kb = ki * 32 + (lane >> 4) * 8 + (e & 4);  // 4 contiguous k (hidden-1)

  {  // W2p chunk
    __bf16 v[4];
#pragma unroll
    for (int j = 0; j < 4; ++j) v[j] = (__bf16)W2[(kb + j) * NH + n];
    *(bf16x4*)(W2p + e) = *(bf16x4*)v;
  }
  {  // Mp chunk
    float acc[4] = {0.f, 0.f, 0.f, 0.f};
    for (int i = 0; i < ND; ++i) {
      float w3 = W3[n * ND + i];
      float4 u = *(const float4*)&W1[i * NH + kb];
      acc[0] += w3 * u.x; acc[1] += w3 * u.y;
      acc[2] += w3 * u.z; acc[3] += w3 * u.w;
    }
    __bf16 v[4];
#pragma unroll
    for (int j = 0; j < 4; ++j)
      v[j] = (__bf16)(W2[(kb + j) * NH + n] * acc[j]);
    *(bf16x4*)(Mp + e) = *(bf16x4*)v;
  }
}

// ---------------------------------------------------------------------------
// Kernel 1 (fused main): grid 512, block = (32-row group rb, 64-col eighth q).
// LDS 77 KB -> 2 blocks/CU, 2 waves/SIMD (latency hiding for L2 B-streams).
//  (0) build bf16 x A-frag in LDS (2 row-tiles x K=64 padded)
//  (1) H1 = x@W1 via MFMA; tanh/1-h^2 -> LDS A-frag packs (all 512 h1 cols)
//  (2) dual MFMA GEMM over this block's 64 h2 cols: accH=H1@W2, accM=D1@M
//  (3) h2=tanh(accH+b2) -> LDS; div partials (shuffle+LDS+atomicAdd)
//  (4) dx = h2 @ W3 (this eighth's 64 k), atomicAdd (out pre-zeroed)
// ---------------------------------------------------------------------------
__global__ __launch_bounds__(256) void k_main(
    const float* __restrict__ x, const float* __restrict__ t,
    const __bf16* __restrict__ W1p, const float* __restrict__ b1,
    const __bf16* __restrict__ W2p, const __bf16* __restrict__ Mp,
    const float* __restrict__ b2, const float* __restrict__ W3T,
    const float* __restrict__ b3, float* __restrict__ out) {
  __shared__ __bf16 xf[2 * 2 * 64 * 8];  // x A-frag, 4 KB
  __shared__ __bf16 aH[2 * 16 * 64 * 8]; // H1 A-frag, 32 KB
  __shared__ __bf16 aD[2 * 16 * 64 * 8]; // D1 A-frag, 32 KB
  __shared__ float h2s[32][68];          // h2 tile (64 + 4 pad), 8.5 KB
  __shared__ float divred[4][32];

  int bid = blockIdx.x;  // 0..511
  int rb = bid >> 3;     // 32-row group 0..63
  int q = bid & 7;       // 64-col eighth of hidden-2
  int tid = threadIdx.x;
  int w = tid >> 6, lane = tid & 63;
  int col = lane & 15, quad = lane >> 4;
  float tv = t[0];

  // ---- phase 0: build x A-frag (one thread per (rt,ki,lane)) ----
  {
    int lane0 = tid & 63;
    int ki0 = (tid >> 6) & 1;
    int rt0 = tid >> 7;
    int row = rb * 32 + rt0 * 16 + (lane0 & 15);
    int k0 = ki0 * 32 + (lane0 >> 4) * 8;
    __bf16 v[8];
#pragma unroll
    for (int j = 0; j < 8; ++j) {
      int k = k0 + j;
      float val = (k < ND) ? x[(long)row * (ND + 1) + k] : (k == ND ? tv : 0.f);
      v[j] = (__bf16)val;
    }
    *(bf16x8*)(xf + (long)tid * 8) = *(bf16x8*)v;
  }
  __syncthreads();

  // ---- phase 1: H1/D1 via MFMA -> LDS A-frags ----
  {
    bf16x8 xa[2][2];
#pragma unroll
    for (int rt = 0; rt < 2; ++rt)
#pragma unroll
      for (int ki = 0; ki < 2; ++ki)
        xa[rt][ki] = *(const bf16x8*)(xf + ((rt * 2 + ki) * 64 + lane) * 8);
#pragma unroll 2
    for (int c8 = 0; c8 < 8; ++c8) {
      int ct1 = w * 8 + c8;  // h1 col-tile 0..31
      floatx4 ac0 = {0, 0, 0, 0}, ac1 = {0, 0, 0, 0};
#pragma unroll
      for (int ki = 0; ki < 2; ++ki) {
        bf16x8 bw = *(const bf16x8*)(W1p + ((long)(ct1 * 2 + ki) * 64 + lane) * 8);
        ac0 = __builtin_amdgcn_mfma_f32_16x16x32_bf16(xa[0][ki], bw, ac0, 0, 0, 0);
        ac1 = __builtin_amdgcn_mfma_f32_16x16x32_bf16(xa[1][ki], bw, ac1, 0, 0, 0);
      }
      int n = ct1 * 16 + col;
      float bb = b1[n];
      int kio = n >> 5, hi = (n >> 3) & 3, j = n & 7;
#pragma unroll
      for (int rt = 0; rt < 2; ++rt) {
        floatx4 a = rt ? ac1 : ac0;
#pragma unroll
        for (int r = 0; r < 4; ++r) {
          float h = fast_tanh(a[r] + bb);
          int lanep = (quad * 4 + r) | (hi << 4);
          int ofs = ((rt * 16 + kio) * 64 + lanep) * 8 + j;
          aH[ofs] = (__bf16)h;
          aD[ofs] = (__bf16)(1.f - h * h);
        }
      }
    }
  }
  __syncthreads();

  // ---- phase 2: dual MFMA GEMM (2 row-tiles x 1 col-tile per wave) ----
  int ct0 = q * 4 + w;  // this wave's global h2 col-tile
  floatx4 accH[2] = {{0,0,0,0},{0,0,0,0}};
  floatx4 accM[2] = {{0,0,0,0},{0,0,0,0}};
#pragma unroll 4
  for (int ki = 0; ki < NKI; ++ki) {
    bf16x8 ah0 = *(const bf16x8*)(aH + ((0 * 16 + ki) * 64 + lane) * 8);
    bf16x8 ah1 = *(const bf16x8*)(aH + ((1 * 16 + ki) * 64 + lane) * 8);
    bf16x8 ad0 = *(const bf16x8*)(aD + ((0 * 16 + ki) * 64 + lane) * 8);
    bf16x8 ad1 = *(const bf16x8*)(aD + ((1 * 16 + ki) * 64 + lane) * 8);
    long boff = ((long)(ct0 * NKI + ki) * 64 + lane) * 8;
    bf16x8 bw = *(const bf16x8*)(W2p + boff);
    bf16x8 bm = *(const bf16x8*)(Mp + boff);
    accH[0] = __builtin_amdgcn_mfma_f32_16x16x32_bf16(ah0, bw, accH[0], 0, 0, 0);
    accH[1] = __builtin_amdgcn_mfma_f32_16x16x32_bf16(ah1, bw, accH[1], 0, 0, 0);
    accM[0] = __builtin_amdgcn_mfma_f32_16x16x32_bf16(ad0, bm, accM[0], 0, 0, 0);
    accM[1] = __builtin_amdgcn_mfma_f32_16x16x32_bf16(ad1, bm, accM[1], 0, 0, 0);
  }

  // ---- phase 3: h2 -> LDS, divergence partials ----
  float divv[2][4] = {{0, 0, 0, 0}, {0, 0, 0, 0}};
  {
    int n = ct0 * 16 + col;   // global hidden-2 col
    int nc = w * 16 + col;    // local col within 64
    float bb = b2[n];
#pragma unroll
    for (int rt = 0; rt < 2; ++rt) {
#pragma unroll
      for (int r = 0; r < 4; ++r) {
        float h2 = fast_tanh(accH[rt][r] + bb);
        h2s[rt * 16 + quad * 4 + r][nc] = h2;
        divv[rt][r] += accM[rt][r] * (1.f - h2 * h2);
      }
    }
  }
#pragma unroll
  for (int rt = 0; rt < 2; ++rt) {
#pragma unroll
    for (int r = 0; r < 4; ++r) {
      float v = divv[rt][r];
      v += __shfl_xor(v, 1);
      v += __shfl_xor(v, 2);
      v += __shfl_xor(v, 4);
      v += __shfl_xor(v, 8);
      if (col == 0) divred[w][rt * 16 + quad * 4 + r] = v;
    }
  }
  __syncthreads();
  if (tid < 32) {
    float v = divred[0][tid] + divred[1][tid] + divred[2][tid] + divred[3][tid];
    atomicAdd(&out[(long)(rb * 32 + tid) * (ND + 1) + ND], v);
  }

  // ---- phase 4: dx = h2 @ W3 (this eighth's 64 k) ----
  int row = tid & 31;  // local row
  int i0 = tid >> 5;   // 0..7 -> output cols i0*4 .. i0*4+3
  float a4[4] = {0.f, 0.f, 0.f, 0.f};
#pragma unroll 4
  for (int kk = 0; kk < 64; kk += 4) {
    float4 h = *(const float4*)&h2s[row][kk];
#pragma unroll
    for (int ii = 0; ii < 4; ++ii) {
      float4 wv = *(const float4*)&W3T[(long)(i0 * 4 + ii) * NH + q * 64 + kk];
      a4[ii] += h.x * wv.x + h.y * wv.y + h.z * wv.z + h.w * wv.w;
    }
  }
  float* orow = out + (long)(rb * 32 + row) * (ND + 1);
#pragma unroll
  for (int ii = 0; ii < 4; ++ii) {
    float v = a4[ii] + (q == 0 ? b3[i0 * 4 + ii] : 0.f);
    atomicAdd(&orow[i0 * 4 + ii], v);
  }
}

// ---------------------------------------------------------------------------
extern "C" void kernel_launch(void* const* d_in, const int* in_sizes, int n_in,
                              void* d_out, int out_size, void* d_ws, size_t ws_size,
                              hipStream_t stream) {
  const float* t  = (const float*)d_in[0];
  const float* x  = (const float*)d_in[1];
  const float* W1 = (const float*)d_in[2];
  const float* b1 = (const float*)d_in[3];
  const float* W2 = (const float*)d_in[4];
  const float* b2 = (const float*)d_in[5];
  const float* W3 = (const float*)d_in[6];
  const float* b3 = (const float*)d_in[7];
  float* out = (float*)d_out;

  __bf16* W2p = (__bf16*)d_ws;            // 512*512 bf16
  __bf16* Mp  = W2p + NH * NH;            // 512*512 bf16
  float*  W3T = (float*)(Mp + NH * NH);   // 32*512 fp32
  __bf16* W1p = (__bf16*)(W3T + ND * NH); // 32*2*64*8 = 32768 bf16

  k_pre<<<256, 256, 0, stream>>>(W1, W2, W3, W2p, Mp, W3T, W1p, out);
  k_main<<<512, 256, 0, stream>>>(x, t, W1p, b1, W2p, Mp, b2, W3T, b3, out);
}

// Round 7
// 96.508 us; speedup vs baseline: 1.0895x; 1.0895x over previous
//
#include <hip/hip_runtime.h>
#include <math.h>

// Problem sizes
constexpr int NB = 2048;  // batch
constexpr int ND = 32;    // data dim (x has ND+1 cols; col ND is replaced by t)
constexpr int NH = 512;   // hidden
constexpr int NKI = NH / 32;  // K-iterations of 32 per MFMA chain = 16

typedef __bf16 bf16x8 __attribute__((ext_vector_type(8)));
typedef __bf16 bf16x4 __attribute__((ext_vector_type(4)));
typedef float floatx4 __attribute__((ext_vector_type(4)));

__device__ inline float fast_tanh(float x) {
  float e = __expf(2.f * x);
  return 1.f - 2.f / (e + 1.f);
}

// Fragment pack index: elem = ((tile*nki + ki)*64 + lane)*8 + j
// A-frag (16x16x32): row m = tile*16 + (lane&15), k = ki*32 + (lane>>4)*8 + j
// B-frag:            col n = tile*16 + (lane&15), k = ki*32 + (lane>>4)*8 + j
// C/D frag:          col = lane&15, row = (lane>>4)*4 + reg   [m89-verified]

// ---------------------------------------------------------------------------
// Kernel 0: weight prep, load-balanced: every thread packs a 4-elem chunk of
// BOTH W2p and Mp (M[j,n] = W2[j,n]*G[n,j], G[n,j]=sum_i W3[n,i]*W1[i,j]).
// Also W3T (32x512 transpose), W1p (B-frag, K padded to 64), zero d_out.
// ---------------------------------------------------------------------------
__global__ __launch_bounds__(256) void k_pre(
    const float* __restrict__ W1, const float* __restrict__ W2,
    const float* __restrict__ W3, __bf16* __restrict__ W2p,
    __bf16* __restrict__ Mp, float* __restrict__ W3T,
    __bf16* __restrict__ W1p, float* __restrict__ out) {
  int g = blockIdx.x * 256 + threadIdx.x;  // 0..65535
  for (int idx = g; idx < NB * (ND + 1); idx += 65536) out[idx] = 0.f;
  if (g < ND * NH)  // W3T[i][k] = W3[k][i]
    W3T[g] = W3[(g & (NH - 1)) * ND + (g >> 9)];
  if (g < 4096) {   // W1p: ct(32) x ki(2) x lane(64), 8 bf16 each
    int lane1 = g & 63;
    int ki1 = (g >> 6) & 1;
    int ct1 = g >> 7;
    int n1 = ct1 * 16 + (lane1 & 15);
    int k0 = ki1 * 32 + (lane1 >> 4) * 8;
    __bf16 v[8];
#pragma unroll
    for (int j = 0; j < 8; ++j) {
      int k = k0 + j;
      v[j] = (k <= ND) ? (__bf16)W1[k * NH + n1] : (__bf16)0.f;
    }
    *(bf16x8*)(W1p + (long)g * 8) = *(bf16x8*)v;
  }

  // 4-element chunk coords within the B-frag pack
  int e = g * 4;                        // 0..262143, multiple of 4
  int lane = (e >> 3) & 63;
  int ki = (e >> 9) & (NKI - 1);
  int ct = e >> 13;                     // 0..31
  int n = ct * 16 + (lane & 15);        // output column (hidden-2 index)
  int kb = ki * 32 + (lane >> 4) * 8 + (e & 4);  // 4 contiguous k (hidden-1)

  {  // W2p chunk
    __bf16 v[4];
#pragma unroll
    for (int j = 0; j < 4; ++j) v[j] = (__bf16)W2[(kb + j) * NH + n];
    *(bf16x4*)(W2p + e) = *(bf16x4*)v;
  }
  {  // Mp chunk
    float acc[4] = {0.f, 0.f, 0.f, 0.f};
    for (int i = 0; i < ND; ++i) {
      float w3 = W3[n * ND + i];
      float4 u = *(const float4*)&W1[i * NH + kb];
      acc[0] += w3 * u.x; acc[1] += w3 * u.y;
      acc[2] += w3 * u.z; acc[3] += w3 * u.w;
    }
    __bf16 v[4];
#pragma unroll
    for (int j = 0; j < 4; ++j)
      v[j] = (__bf16)(W2[(kb + j) * NH + n] * acc[j]);
    *(bf16x4*)(Mp + e) = *(bf16x4*)v;
  }
}

// ---------------------------------------------------------------------------
// Kernel 1 (fused main): block = (32-row group rb, col quarter q). Phases:
//  (0) build bf16 x A-frag in LDS (2 row-tiles x K=64 padded)
//  (1) H1 = x@W1 via MFMA; tanh/1-h^2 -> LDS A-frag packs (all 512 h1 cols)
//  (2) dual MFMA GEMM over this block's 128 h2 cols: accH=H1@W2, accM=D1@M
//  (3) h2=tanh(accH+b2) -> LDS; div partials (shuffle+LDS+atomicAdd)
//  (4) dx = h2 @ W3 (this quarter's 128 k), atomicAdd (out pre-zeroed)
// [R6 post-mortem: 64-col/512-block split regressed (8x phase-1 dup + 2x
//  atomics beat the occupancy gain) — this 128-col/256-block shape is best.]
// ---------------------------------------------------------------------------
__global__ __launch_bounds__(256) void k_main(
    const float* __restrict__ x, const float* __restrict__ t,
    const __bf16* __restrict__ W1p, const float* __restrict__ b1,
    const __bf16* __restrict__ W2p, const __bf16* __restrict__ Mp,
    const float* __restrict__ b2, const float* __restrict__ W3T,
    const float* __restrict__ b3, float* __restrict__ out) {
  __shared__ __bf16 xf[2 * 2 * 64 * 8];  // x A-frag, 4 KB
  __shared__ __bf16 aH[2 * 16 * 64 * 8]; // H1 A-frag, 32 KB
  __shared__ __bf16 aD[2 * 16 * 64 * 8]; // D1 A-frag, 32 KB
  __shared__ float h2s[32][132];         // h2 tile, +4 pad
  __shared__ float divred[4][32];

  int bid = blockIdx.x;  // 0..255
  int rb = bid >> 2;     // 32-row group 0..63
  int q = bid & 3;       // col quarter of hidden-2
  int tid = threadIdx.x;
  int w = tid >> 6, lane = tid & 63;
  int col = lane & 15, quad = lane >> 4;
  float tv = t[0];

  // ---- phase 0: build x A-frag (one thread per (rt,ki,lane)) ----
  {
    int lane0 = tid & 63;
    int ki0 = (tid >> 6) & 1;
    int rt0 = tid >> 7;
    int row = rb * 32 + rt0 * 16 + (lane0 & 15);
    int k0 = ki0 * 32 + (lane0 >> 4) * 8;
    __bf16 v[8];
#pragma unroll
    for (int j = 0; j < 8; ++j) {
      int k = k0 + j;
      float val = (k < ND) ? x[(long)row * (ND + 1) + k] : (k == ND ? tv : 0.f);
      v[j] = (__bf16)val;
    }
    *(bf16x8*)(xf + (long)tid * 8) = *(bf16x8*)v;
  }
  __syncthreads();

  // ---- phase 1: H1/D1 via MFMA -> LDS A-frags ----
  {
    bf16x8 xa[2][2];
#pragma unroll
    for (int rt = 0; rt < 2; ++rt)
#pragma unroll
      for (int ki = 0; ki < 2; ++ki)
        xa[rt][ki] = *(const bf16x8*)(xf + ((rt * 2 + ki) * 64 + lane) * 8);
#pragma unroll 2
    for (int c8 = 0; c8 < 8; ++c8) {
      int ct1 = w * 8 + c8;  // h1 col-tile 0..31
      floatx4 ac0 = {0, 0, 0, 0}, ac1 = {0, 0, 0, 0};
#pragma unroll
      for (int ki = 0; ki < 2; ++ki) {
        bf16x8 bw = *(const bf16x8*)(W1p + ((long)(ct1 * 2 + ki) * 64 + lane) * 8);
        ac0 = __builtin_amdgcn_mfma_f32_16x16x32_bf16(xa[0][ki], bw, ac0, 0, 0, 0);
        ac1 = __builtin_amdgcn_mfma_f32_16x16x32_bf16(xa[1][ki], bw, ac1, 0, 0, 0);
      }
      int n = ct1 * 16 + col;
      float bb = b1[n];
      int kio = n >> 5, hi = (n >> 3) & 3, j = n & 7;
#pragma unroll
      for (int rt = 0; rt < 2; ++rt) {
        floatx4 a = rt ? ac1 : ac0;
#pragma unroll
        for (int r = 0; r < 4; ++r) {
          float h = fast_tanh(a[r] + bb);
          int lanep = (quad * 4 + r) | (hi << 4);
          int ofs = ((rt * 16 + kio) * 64 + lanep) * 8 + j;
          aH[ofs] = (__bf16)h;
          aD[ofs] = (__bf16)(1.f - h * h);
        }
      }
    }
  }
  __syncthreads();

  // ---- phase 2: dual MFMA GEMM (2 row-tiles x 2 col-tiles per wave) ----
  int ct0 = q * 8 + w * 2;  // this wave's first global h2 col-tile
  floatx4 accH[2][2] = {{{0,0,0,0},{0,0,0,0}},{{0,0,0,0},{0,0,0,0}}};
  floatx4 accM[2][2] = {{{0,0,0,0},{0,0,0,0}},{{0,0,0,0},{0,0,0,0}}};
#pragma unroll 2
  for (int ki = 0; ki < NKI; ++ki) {
    bf16x8 ah0 = *(const bf16x8*)(aH + ((0 * 16 + ki) * 64 + lane) * 8);
    bf16x8 ah1 = *(const bf16x8*)(aH + ((1 * 16 + ki) * 64 + lane) * 8);
    bf16x8 ad0 = *(const bf16x8*)(aD + ((0 * 16 + ki) * 64 + lane) * 8);
    bf16x8 ad1 = *(const bf16x8*)(aD + ((1 * 16 + ki) * 64 + lane) * 8);
#pragma unroll
    for (int cc = 0; cc < 2; ++cc) {
      long boff = ((long)((ct0 + cc) * NKI + ki) * 64 + lane) * 8;
      bf16x8 bw = *(const bf16x8*)(W2p + boff);
      bf16x8 bm = *(const bf16x8*)(Mp + boff);
      accH[0][cc] = __builtin_amdgcn_mfma_f32_16x16x32_bf16(ah0, bw, accH[0][cc], 0, 0, 0);
      accH[1][cc] = __builtin_amdgcn_mfma_f32_16x16x32_bf16(ah1, bw, accH[1][cc], 0, 0, 0);
      accM[0][cc] = __builtin_amdgcn_mfma_f32_16x16x32_bf16(ad0, bm, accM[0][cc], 0, 0, 0);
      accM[1][cc] = __builtin_amdgcn_mfma_f32_16x16x32_bf16(ad1, bm, accM[1][cc], 0, 0, 0);
    }
  }

  // ---- phase 3: h2 -> LDS, divergence partials ----
  float divv[2][4] = {{0, 0, 0, 0}, {0, 0, 0, 0}};
#pragma unroll
  for (int cc = 0; cc < 2; ++cc) {
    int n = (ct0 + cc) * 16 + col;     // global hidden-2 col
    int nc = (w * 2 + cc) * 16 + col;  // local col within 128
    float bb = b2[n];
#pragma unroll
    for (int rt = 0; rt < 2; ++rt) {
#pragma unroll
      for (int r = 0; r < 4; ++r) {
        float h2 = fast_tanh(accH[rt][cc][r] + bb);
        h2s[rt * 16 + quad * 4 + r][nc] = h2;
        divv[rt][r] += accM[rt][cc][r] * (1.f - h2 * h2);
      }
    }
  }
#pragma unroll
  for (int rt = 0; rt < 2; ++rt) {
#pragma unroll
    for (int r = 0; r < 4; ++r) {
      float v = divv[rt][r];
      v += __shfl_xor(v, 1);
      v += __shfl_xor(v, 2);
      v += __shfl_xor(v, 4);
      v += __shfl_xor(v, 8);
      if (col == 0) divred[w][rt * 16 + quad * 4 + r] = v;
    }
  }
  __syncthreads();
  if (tid < 32) {
    float v = divred[0][tid] + divred[1][tid] + divred[2][tid] + divred[3][tid];
    atomicAdd(&out[(long)(rb * 32 + tid) * (ND + 1) + ND], v);
  }

  // ---- phase 4: dx = h2 @ W3 (this quarter's 128 k) ----
  int row = tid & 31;  // local row
  int i0 = tid >> 5;   // 0..7 -> output cols i0*4 .. i0*4+3
  float a4[4] = {0.f, 0.f, 0.f, 0.f};
#pragma unroll 2
  for (int kk = 0; kk < 128; kk += 4) {
    float4 h = *(const float4*)&h2s[row][kk];
#pragma unroll
    for (int ii = 0; ii < 4; ++ii) {
      float4 wv = *(const float4*)&W3T[(long)(i0 * 4 + ii) * NH + q * 128 + kk];
      a4[ii] += h.x * wv.x + h.y * wv.y + h.z * wv.z + h.w * wv.w;
    }
  }
  float* orow = out + (long)(rb * 32 + row) * (ND + 1);
#pragma unroll
  for (int ii = 0; ii < 4; ++ii) {
    float v = a4[ii] + (q == 0 ? b3[i0 * 4 + ii] : 0.f);
    atomicAdd(&orow[i0 * 4 + ii], v);
  }
}

// ---------------------------------------------------------------------------
extern "C" void kernel_launch(void* const* d_in, const int* in_sizes, int n_in,
                              void* d_out, int out_size, void* d_ws, size_t ws_size,
                              hipStream_t stream) {
  const float* t  = (const float*)d_in[0];
  const float* x  = (const float*)d_in[1];
  const float* W1 = (const float*)d_in[2];
  const float* b1 = (const float*)d_in[3];
  const float* W2 = (const float*)d_in[4];
  const float* b2 = (const float*)d_in[5];
  const float* W3 = (const float*)d_in[6];
  const float* b3 = (const float*)d_in[7];
  float* out = (float*)d_out;

  __bf16* W2p = (__bf16*)d_ws;            // 512*512 bf16
  __bf16* Mp  = W2p + NH * NH;            // 512*512 bf16
  float*  W3T = (float*)(Mp + NH * NH);   // 32*512 fp32
  __bf16* W1p = (__bf16*)(W3T + ND * NH); // 32*2*64*8 = 32768 bf16

  k_pre<<<256, 256, 0, stream>>>(W1, W2, W3, W2p, Mp, W3T, W1p, out);
  k_main<<<256, 256, 0, stream>>>(x, t, W1p, b1, W2p, Mp, b2, W3T, b3, out);
}